// Round 3
// baseline (605.671 us; speedup 1.0000x reference)
//
#include <hip/hip_runtime.h>
#include <stdint.h>

typedef unsigned short u16;
typedef __bf16 bf16x8 __attribute__((ext_vector_type(8)));
typedef unsigned short u16x8 __attribute__((ext_vector_type(8)));
typedef u16x8 u16x8_ma __attribute__((may_alias));
typedef unsigned short u16x4 __attribute__((ext_vector_type(4)));
typedef float f32x4 __attribute__((ext_vector_type(4)));

#define DIN   1024
#define DOUT  4096
#define BM    128
#define BN    128
#define BK    64

__device__ __forceinline__ u16 f2bf(float f) {
  unsigned u = __float_as_uint(f);
  u += 0x7fffu + ((u >> 16) & 1u);   // round-to-nearest-even (finite inputs)
  return (u16)(u >> 16);
}
__device__ __forceinline__ bf16x8 ldfrag(const u16* p) {
  union { u16x8 u; bf16x8 b; } cv;
  cv.u = *(const u16x8_ma*)p;
  return cv.b;
}
__device__ __forceinline__ f32x4 mfma16(bf16x8 a, bf16x8 b, f32x4 c) {
  return __builtin_amdgcn_mfma_f32_16x16x32_bf16(a, b, c, 0, 0, 0);
}
__device__ __forceinline__ void gload_lds16(const u16* g, u16* l) {
  __builtin_amdgcn_global_load_lds(
      (const __attribute__((address_space(1))) void*)g,
      (__attribute__((address_space(3))) void*)l, 16, 0, 0);
}

// fp32 -> bf16 bulk convert (vectorized, grid-stride over float4s)
__global__ void cvt_f32_bf16(const float* __restrict__ src, u16* __restrict__ dst, int n4) {
  int i = blockIdx.x * blockDim.x + threadIdx.x;
  const int stride = gridDim.x * blockDim.x;
  for (; i < n4; i += stride) {
    f32x4 v = ((const f32x4*)src)[i];
    u16x4 o;
    o.x = f2bf(v.x); o.y = f2bf(v.y); o.z = f2bf(v.z); o.w = f2bf(v.w);
    ((u16x4*)dst)[i] = o;
  }
}

// Convert + transpose blueprint weights (fp32 in, bf16 out):
// W1 [S][C][H] -> W1T [S][H][C] ;  W2 [S][H][C] -> W2T [S][C][H]
__global__ void prep_transpose(const float* __restrict__ W1, const float* __restrict__ W2,
                               u16* __restrict__ W1T, u16* __restrict__ W2T) {
  const int s = blockIdx.x;
  const int t = threadIdx.x;
  const float* w1 = W1 + s * 8192;   // [64 c][128 h]
  u16* w1t = W1T + s * 8192;         // [128 h][64 c]
  for (int i = t; i < 8192; i += 256) {
    int c = i >> 7, h = i & 127;
    w1t[h * 64 + c] = f2bf(w1[i]);
  }
  const float* w2 = W2 + s * 8192;   // [128 h][64 c]
  u16* w2t = W2T + s * 8192;         // [64 c][128 h]
  for (int i = t; i < 8192; i += 256) {
    int h = i >> 6, c = i & 63;
    w2t[c * 128 + h] = f2bf(w2[i]);
  }
}

// Fused: base = x@Wb^T + bb (128x128 tile, m97 structure, bf16 staged inputs),
// then per-wave (one seed per wave column-half) blueprint MLP + alpha blend.
// Biases/alpha stay fp32 (exact); output fp32.
__global__ __launch_bounds__(256, 2) void kasmina_fused(
    const u16* __restrict__ X,   const u16* __restrict__ Wb,   // bf16 (pre-converted)
    const float* __restrict__ bb,  const float* __restrict__ b1,
    const float* __restrict__ b2,  const float* __restrict__ alpha,
    const int* __restrict__ active,
    const u16* __restrict__ W1T, const u16* __restrict__ W2T,  // bf16
    float* __restrict__ out)
{
  // LDS: staging As[128][64] @0, Bs[128][64] @8192. Epilogue reuses it as 4
  // wave-private regions of 4608 el: Ys[32][72] + Hs[32][72] (stride 72).
  __shared__ u16 lds[18432];

  const int t = threadIdx.x;
  const int w = t >> 6, l = t & 63;
  const int wm = w >> 1, wn = w & 1;
  const int lane15 = l & 15, quad = l >> 4;
  const int bn0 = blockIdx.x * BN;
  const int bm0 = blockIdx.y * BM;

  f32x4 acc[4][4];
#pragma unroll
  for (int mt = 0; mt < 4; ++mt)
#pragma unroll
    for (int nt = 0; nt < 4; ++nt)
      acc[mt][nt] = (f32x4){0.f, 0.f, 0.f, 0.f};

  const int srow = l >> 3;
  const int scol = (l & 7) << 3;
  const u16* xg = X  + (size_t)(bm0 + srow) * DIN + scol;
  const u16* wg = Wb + (size_t)(bn0 + srow) * DIN + scol;

  for (int kt = 0; kt < DIN / BK; ++kt) {
    const int k0 = kt * BK;
#pragma unroll
    for (int i = 0; i < 4; ++i) {
      const int q = i * 4 + w;                       // chunk: rows q*8..q*8+7
      gload_lds16(xg + (size_t)(q * 8) * DIN + k0, &lds[q * 512]);
      gload_lds16(wg + (size_t)(q * 8) * DIN + k0, &lds[8192 + q * 512]);
    }
    __syncthreads();
    const u16* Ab = &lds[(wm * 64 + lane15) * 64];
    const u16* Bb = &lds[8192 + (wn * 64 + lane15) * 64];
#pragma unroll
    for (int ks = 0; ks < 2; ++ks) {
      bf16x8 af[4], bfx[4];
#pragma unroll
      for (int mt = 0; mt < 4; ++mt) af[mt] = ldfrag(Ab + mt * 1024 + ks * 32 + quad * 8);
#pragma unroll
      for (int nt = 0; nt < 4; ++nt) bfx[nt] = ldfrag(Bb + nt * 1024 + ks * 32 + quad * 8);
#pragma unroll
      for (int mt = 0; mt < 4; ++mt)
#pragma unroll
        for (int nt = 0; nt < 4; ++nt)
          acc[mt][nt] = mfma16(af[mt], bfx[nt], acc[mt][nt]);
    }
    __syncthreads();   // final iter: also releases As/Bs for epilogue reuse
  }

  // ---------------- epilogue: per-seed MLP + blend ----------------
  const int sidx = blockIdx.x * 2 + wn;              // wave's seed
  const float al = alpha[sidx];
  const float aval = (active[sidx] != 0) ? al : 0.0f;
  float bbv[4];
#pragma unroll
  for (int nt = 0; nt < 4; ++nt) bbv[nt] = bb[sidx * 64 + nt * 16 + lane15];

  u16* Yw = &lds[w * 4608];        // [32][72]
  u16* Hw = Yw + 2304;             // [32][72]
  const size_t orow0 = (size_t)(bm0 + wm * 64);

#pragma unroll 1
  for (int mh = 0; mh < 2; ++mh) {   // 32-row halves
    // y (=base chunk incl. bias) -> LDS bf16, A-operand [m][c] layout.
#pragma unroll
    for (int mt = 0; mt < 2; ++mt)
#pragma unroll
      for (int nt = 0; nt < 4; ++nt) {
        f32x4 v = acc[mh * 2 + mt][nt];
        const int col = nt * 16 + lane15;
#pragma unroll
        for (int r = 0; r < 4; ++r)
          Yw[(mt * 16 + quad * 4 + r) * 72 + col] = f2bf(v[r] + bbv[nt]);
      }
    __syncthreads();               // Yw write -> read fence (uniform flow)

    f32x4 bp[2][4];
#pragma unroll
    for (int nt = 0; nt < 4; ++nt) {
      const float b2v = b2[sidx * 64 + nt * 16 + lane15];
      const f32x4 tv = (f32x4){b2v, b2v, b2v, b2v};
      bp[0][nt] = tv; bp[1][nt] = tv;
    }

#pragma unroll 1
    for (int hh = 0; hh < 2; ++hh) {  // H=128 in two halves of 64
      f32x4 hc[2][4];
#pragma unroll
      for (int nt = 0; nt < 4; ++nt) {
        const float b1v = b1[sidx * 128 + hh * 64 + nt * 16 + lane15];
        const f32x4 tv = (f32x4){b1v, b1v, b1v, b1v};
        hc[0][nt] = tv; hc[1][nt] = tv;
      }
      // GEMM1: h = y @ W1_s   (M=32, N=64(half), K=64)
      const u16* w1b = W1T + sidx * 8192 + (hh * 64 + lane15) * 64 + quad * 8;
#pragma unroll
      for (int ks = 0; ks < 2; ++ks) {
        bf16x8 af0 = ldfrag(Yw + lane15 * 72 + ks * 32 + quad * 8);
        bf16x8 af1 = ldfrag(Yw + (16 + lane15) * 72 + ks * 32 + quad * 8);
#pragma unroll
        for (int nt = 0; nt < 4; ++nt) {
          bf16x8 bfr = ldfrag(w1b + nt * 1024 + ks * 32);   // L2-hot
          hc[0][nt] = mfma16(af0, bfr, hc[0][nt]);
          hc[1][nt] = mfma16(af1, bfr, hc[1][nt]);
        }
      }
      // relu -> bf16 -> Hs
#pragma unroll
      for (int mt = 0; mt < 2; ++mt)
#pragma unroll
        for (int nt = 0; nt < 4; ++nt) {
          f32x4 v = hc[mt][nt];
          const int col = nt * 16 + lane15;
#pragma unroll
          for (int r = 0; r < 4; ++r) {
            float hv = v[r] > 0.f ? v[r] : 0.f;
            Hw[(mt * 16 + quad * 4 + r) * 72 + col] = f2bf(hv);
          }
        }
      __syncthreads();             // Hw write -> read fence
      // GEMM2: bp += h @ W2_s[half]   (M=32, N=64, K=64)
      const u16* w2b = W2T + sidx * 8192 + lane15 * 128 + hh * 64 + quad * 8;
#pragma unroll
      for (int ks = 0; ks < 2; ++ks) {
        bf16x8 af0 = ldfrag(Hw + lane15 * 72 + ks * 32 + quad * 8);
        bf16x8 af1 = ldfrag(Hw + (16 + lane15) * 72 + ks * 32 + quad * 8);
#pragma unroll
        for (int nt = 0; nt < 4; ++nt) {
          bf16x8 bfr = ldfrag(w2b + nt * 2048 + ks * 32);
          bp[0][nt] = mfma16(af0, bfr, bp[0][nt]);
          bp[1][nt] = mfma16(af1, bfr, bp[1][nt]);
        }
      }
      __syncthreads();             // Hw read -> next-iter write fence
    }
    // blend (y in fp32 from acc, unquantized) + fp32 store
#pragma unroll
    for (int mt = 0; mt < 2; ++mt)
#pragma unroll
      for (int nt = 0; nt < 4; ++nt) {
        f32x4 yv = acc[mh * 2 + mt][nt];
        f32x4 pv = bp[mt][nt];
        const int col = sidx * 64 + nt * 16 + lane15;
#pragma unroll
        for (int r = 0; r < 4; ++r) {
          const float y = yv[r] + bbv[nt];
          const float o = (1.0f - aval) * y + aval * pv[r];
          const size_t row = orow0 + mh * 32 + mt * 16 + quad * 4 + r;
          out[row * DOUT + col] = o;
        }
      }
    __syncthreads();               // fence Yw/Hw reuse for mh=1
  }
}

extern "C" void kernel_launch(void* const* d_in, const int* in_sizes, int n_in,
                              void* d_out, int out_size, void* d_ws, size_t ws_size,
                              hipStream_t stream) {
  const float* X     = (const float*)d_in[0];   // [8192][1024] fp32
  const float* Wb    = (const float*)d_in[1];   // [4096][1024] fp32
  const float* bbp   = (const float*)d_in[2];   // [4096]
  const float* W1    = (const float*)d_in[3];   // [64][64][128]
  const float* b1p   = (const float*)d_in[4];   // [64][128]
  const float* W2    = (const float*)d_in[5];   // [64][128][64]
  const float* b2p   = (const float*)d_in[6];   // [64][64]
  const float* alpha = (const float*)d_in[7];   // [64]
  const int*  active = (const int*)d_in[8];     // [64]
  float* out = (float*)d_out;

  // workspace layout (u16 units): W1T 512K | W2T 512K | Xb 8.39M | Wbb 4.19M
  u16* W1T = (u16*)d_ws;
  u16* W2T = W1T + 524288;
  u16* Xb  = W1T + 1048576;
  u16* Wbb = W1T + 9437184;       // total ~27.3 MB

  cvt_f32_bf16<<<2048, 256, 0, stream>>>(X,  Xb,  (8192 * 1024) / 4);
  cvt_f32_bf16<<<1024, 256, 0, stream>>>(Wb, Wbb, (4096 * 1024) / 4);
  prep_transpose<<<64, 256, 0, stream>>>(W1, W2, W1T, W2T);
  kasmina_fused<<<dim3(32, 64), 256, 0, stream>>>(
      Xb, Wbb, bbp, b1p, b2p, alpha, active, W1T, W2T, out);
}

// Round 4
// 341.948 us; speedup vs baseline: 1.7712x; 1.7712x over previous
//
#include <hip/hip_runtime.h>
#include <stdint.h>

typedef unsigned short u16;
typedef __bf16 bf16x8 __attribute__((ext_vector_type(8)));
typedef unsigned short u16x8 __attribute__((ext_vector_type(8)));
typedef u16x8 u16x8_ma __attribute__((may_alias));
typedef unsigned short u16x4 __attribute__((ext_vector_type(4)));
typedef float f32x4 __attribute__((ext_vector_type(4)));

#define DIN   1024
#define DOUT  4096
#define BM    128
#define BN    128
#define BK    64

__device__ __forceinline__ u16 f2bf(float f) {
  unsigned u = __float_as_uint(f);
  u += 0x7fffu + ((u >> 16) & 1u);   // round-to-nearest-even (finite inputs)
  return (u16)(u >> 16);
}
__device__ __forceinline__ bf16x8 ldfrag(const u16* p) {
  union { u16x8 u; bf16x8 b; } cv;
  cv.u = *(const u16x8_ma*)p;
  return cv.b;
}
__device__ __forceinline__ f32x4 mfma16(bf16x8 a, bf16x8 b, f32x4 c) {
  return __builtin_amdgcn_mfma_f32_16x16x32_bf16(a, b, c, 0, 0, 0);
}
__device__ __forceinline__ void gload_lds16(const u16* g, u16* l) {
  __builtin_amdgcn_global_load_lds(
      (const __attribute__((address_space(1))) void*)g,
      (__attribute__((address_space(3))) void*)l, 16, 0, 0);
}

// fp32 -> bf16 bulk convert (vectorized, grid-stride over float4s)
__global__ void cvt_f32_bf16(const float* __restrict__ src, u16* __restrict__ dst, int n4) {
  int i = blockIdx.x * blockDim.x + threadIdx.x;
  const int stride = gridDim.x * blockDim.x;
  for (; i < n4; i += stride) {
    f32x4 v = ((const f32x4*)src)[i];
    u16x4 o;
    o.x = f2bf(v.x); o.y = f2bf(v.y); o.z = f2bf(v.z); o.w = f2bf(v.w);
    ((u16x4*)dst)[i] = o;
  }
}

// Convert + transpose blueprint weights via LDS (coalesced global R and W):
// W1 [S][C][H] -> W1T [S][H][C] ;  W2 [S][H][C] -> W2T [S][C][H]
__global__ void prep_transpose(const float* __restrict__ W1, const float* __restrict__ W2,
                               u16* __restrict__ W1T, u16* __restrict__ W2T) {
  __shared__ u16 tile[8192];
  const int s = blockIdx.x;
  const int t = threadIdx.x;

  // ---- W1: [64 c][128 h] -> [128 h][64 c]
  const float* w1 = W1 + s * 8192;
  u16* w1t = W1T + s * 8192;
  for (int i = t; i < 8192; i += 256) tile[i] = f2bf(w1[i]);   // coalesced read
  __syncthreads();
  for (int i = t; i < 8192; i += 256) {                        // coalesced write
    int h = i >> 6, c = i & 63;
    w1t[i] = tile[c * 128 + h];
  }
  __syncthreads();

  // ---- W2: [128 h][64 c] -> [64 c][128 h]
  const float* w2 = W2 + s * 8192;
  u16* w2t = W2T + s * 8192;
  for (int i = t; i < 8192; i += 256) tile[i] = f2bf(w2[i]);
  __syncthreads();
  for (int i = t; i < 8192; i += 256) {
    int c = i >> 7, h = i & 127;
    w2t[i] = tile[h * 64 + c];
  }
}

// Fused: base = x@Wb^T + bb (128x128 tile, m97 structure, bf16 staged inputs),
// then per-wave (one seed per wave column-half) blueprint MLP + alpha blend.
// NOTE: every acc[] index must be a compile-time constant — runtime indexing
// demotes acc to scratch (R3: 2.3 GB HBM writes, 17x amplification).
__global__ __launch_bounds__(256, 2) void kasmina_fused(
    const u16* __restrict__ X,   const u16* __restrict__ Wb,   // bf16 (pre-converted)
    const float* __restrict__ bb,  const float* __restrict__ b1,
    const float* __restrict__ b2,  const float* __restrict__ alpha,
    const int* __restrict__ active,
    const u16* __restrict__ W1T, const u16* __restrict__ W2T,  // bf16
    float* __restrict__ out)
{
  // LDS: staging As[128][64] @0, Bs[128][64] @8192. Epilogue reuses it as 4
  // wave-private regions of 4608 el: Ys[32][72] + Hs[32][72] (stride 72).
  __shared__ u16 lds[18432];

  const int t = threadIdx.x;
  const int w = t >> 6, l = t & 63;
  const int wm = w >> 1, wn = w & 1;
  const int lane15 = l & 15, quad = l >> 4;
  const int bn0 = blockIdx.x * BN;
  const int bm0 = blockIdx.y * BM;

  f32x4 acc[4][4];
#pragma unroll
  for (int mt = 0; mt < 4; ++mt)
#pragma unroll
    for (int nt = 0; nt < 4; ++nt)
      acc[mt][nt] = (f32x4){0.f, 0.f, 0.f, 0.f};

  const int srow = l >> 3;
  const int scol = (l & 7) << 3;
  const u16* xg = X  + (size_t)(bm0 + srow) * DIN + scol;
  const u16* wg = Wb + (size_t)(bn0 + srow) * DIN + scol;

  for (int kt = 0; kt < DIN / BK; ++kt) {
    const int k0 = kt * BK;
#pragma unroll
    for (int i = 0; i < 4; ++i) {
      const int q = i * 4 + w;                       // chunk: rows q*8..q*8+7
      gload_lds16(xg + (size_t)(q * 8) * DIN + k0, &lds[q * 512]);
      gload_lds16(wg + (size_t)(q * 8) * DIN + k0, &lds[8192 + q * 512]);
    }
    __syncthreads();
    const u16* Ab = &lds[(wm * 64 + lane15) * 64];
    const u16* Bb = &lds[8192 + (wn * 64 + lane15) * 64];
#pragma unroll
    for (int ks = 0; ks < 2; ++ks) {
      bf16x8 af[4], bfx[4];
#pragma unroll
      for (int mt = 0; mt < 4; ++mt) af[mt] = ldfrag(Ab + mt * 1024 + ks * 32 + quad * 8);
#pragma unroll
      for (int nt = 0; nt < 4; ++nt) bfx[nt] = ldfrag(Bb + nt * 1024 + ks * 32 + quad * 8);
#pragma unroll
      for (int mt = 0; mt < 4; ++mt)
#pragma unroll
        for (int nt = 0; nt < 4; ++nt)
          acc[mt][nt] = mfma16(af[mt], bfx[nt], acc[mt][nt]);
    }
    __syncthreads();   // final iter: also releases As/Bs for epilogue reuse
  }

  // ---------------- epilogue: per-seed MLP + blend ----------------
  const int sidx = blockIdx.x * 2 + wn;              // wave's seed
  const float al = alpha[sidx];
  const float aval = (active[sidx] != 0) ? al : 0.0f;
  float bbv[4];
#pragma unroll
  for (int nt = 0; nt < 4; ++nt) bbv[nt] = bb[sidx * 64 + nt * 16 + lane15];

  u16* Yw = &lds[w * 4608];        // [32][72]
  u16* Hw = Yw + 2304;             // [32][72]
  const size_t orow0 = (size_t)(bm0 + wm * 64);

#pragma unroll                      // MUST fully unroll: acc[] indices constant
  for (int mh = 0; mh < 2; ++mh) {  // 32-row halves
    // y (=base chunk incl. bias) -> LDS bf16, A-operand [m][c] layout.
#pragma unroll
    for (int mt = 0; mt < 2; ++mt)
#pragma unroll
      for (int nt = 0; nt < 4; ++nt) {
        f32x4 v = acc[mh * 2 + mt][nt];
        const int col = nt * 16 + lane15;
#pragma unroll
        for (int r = 0; r < 4; ++r)
          Yw[(mt * 16 + quad * 4 + r) * 72 + col] = f2bf(v[r] + bbv[nt]);
      }
    __syncthreads();               // Yw write -> read fence (uniform flow)

    f32x4 bp[2][4];
#pragma unroll
    for (int nt = 0; nt < 4; ++nt) {
      const float b2v = b2[sidx * 64 + nt * 16 + lane15];
      const f32x4 tv = (f32x4){b2v, b2v, b2v, b2v};
      bp[0][nt] = tv; bp[1][nt] = tv;
    }

#pragma unroll 1
    for (int hh = 0; hh < 2; ++hh) {  // H=128 in two halves of 64
      f32x4 hc[2][4];
#pragma unroll
      for (int nt = 0; nt < 4; ++nt) {
        const float b1v = b1[sidx * 128 + hh * 64 + nt * 16 + lane15];
        const f32x4 tv = (f32x4){b1v, b1v, b1v, b1v};
        hc[0][nt] = tv; hc[1][nt] = tv;
      }
      // GEMM1: h = y @ W1_s   (M=32, N=64(half), K=64)
      const u16* w1b = W1T + sidx * 8192 + (hh * 64 + lane15) * 64 + quad * 8;
#pragma unroll
      for (int ks = 0; ks < 2; ++ks) {
        bf16x8 af0 = ldfrag(Yw + lane15 * 72 + ks * 32 + quad * 8);
        bf16x8 af1 = ldfrag(Yw + (16 + lane15) * 72 + ks * 32 + quad * 8);
#pragma unroll
        for (int nt = 0; nt < 4; ++nt) {
          bf16x8 bfr = ldfrag(w1b + nt * 1024 + ks * 32);   // L2-hot
          hc[0][nt] = mfma16(af0, bfr, hc[0][nt]);
          hc[1][nt] = mfma16(af1, bfr, hc[1][nt]);
        }
      }
      // relu -> bf16 -> Hs
#pragma unroll
      for (int mt = 0; mt < 2; ++mt)
#pragma unroll
        for (int nt = 0; nt < 4; ++nt) {
          f32x4 v = hc[mt][nt];
          const int col = nt * 16 + lane15;
#pragma unroll
          for (int r = 0; r < 4; ++r) {
            float hv = v[r] > 0.f ? v[r] : 0.f;
            Hw[(mt * 16 + quad * 4 + r) * 72 + col] = f2bf(hv);
          }
        }
      __syncthreads();             // Hw write -> read fence
      // GEMM2: bp += h @ W2_s[half]   (M=32, N=64, K=64)
      const u16* w2b = W2T + sidx * 8192 + lane15 * 128 + hh * 64 + quad * 8;
#pragma unroll
      for (int ks = 0; ks < 2; ++ks) {
        bf16x8 af0 = ldfrag(Hw + lane15 * 72 + ks * 32 + quad * 8);
        bf16x8 af1 = ldfrag(Hw + (16 + lane15) * 72 + ks * 32 + quad * 8);
#pragma unroll
        for (int nt = 0; nt < 4; ++nt) {
          bf16x8 bfr = ldfrag(w2b + nt * 2048 + ks * 32);
          bp[0][nt] = mfma16(af0, bfr, bp[0][nt]);
          bp[1][nt] = mfma16(af1, bfr, bp[1][nt]);
        }
      }
      __syncthreads();             // Hw read -> next-iter write fence
    }
    // blend (y in fp32 from acc, unquantized) + fp32 store
#pragma unroll
    for (int mt = 0; mt < 2; ++mt)
#pragma unroll
      for (int nt = 0; nt < 4; ++nt) {
        f32x4 yv = acc[mh * 2 + mt][nt];
        f32x4 pv = bp[mt][nt];
        const int col = sidx * 64 + nt * 16 + lane15;
#pragma unroll
        for (int r = 0; r < 4; ++r) {
          const float y = yv[r] + bbv[nt];
          const float o = (1.0f - aval) * y + aval * pv[r];
          const size_t row = orow0 + mh * 32 + mt * 16 + quad * 4 + r;
          out[row * DOUT + col] = o;
        }
      }
    __syncthreads();               // fence Yw/Hw reuse for next half
  }
}

extern "C" void kernel_launch(void* const* d_in, const int* in_sizes, int n_in,
                              void* d_out, int out_size, void* d_ws, size_t ws_size,
                              hipStream_t stream) {
  const float* X     = (const float*)d_in[0];   // [8192][1024] fp32
  const float* Wb    = (const float*)d_in[1];   // [4096][1024] fp32
  const float* bbp   = (const float*)d_in[2];   // [4096]
  const float* W1    = (const float*)d_in[3];   // [64][64][128]
  const float* b1p   = (const float*)d_in[4];   // [64][128]
  const float* W2    = (const float*)d_in[5];   // [64][128][64]
  const float* b2p   = (const float*)d_in[6];   // [64][64]
  const float* alpha = (const float*)d_in[7];   // [64]
  const int*  active = (const int*)d_in[8];     // [64]
  float* out = (float*)d_out;

  // workspace layout (u16 units): W1T 512K | W2T 512K | Xb 8.39M | Wbb 4.19M
  u16* W1T = (u16*)d_ws;
  u16* W2T = W1T + 524288;
  u16* Xb  = W1T + 1048576;
  u16* Wbb = W1T + 9437184;       // total ~27.3 MB

  cvt_f32_bf16<<<2048, 256, 0, stream>>>(X,  Xb,  (8192 * 1024) / 4);
  cvt_f32_bf16<<<1024, 256, 0, stream>>>(Wb, Wbb, (4096 * 1024) / 4);
  prep_transpose<<<64, 256, 0, stream>>>(W1, W2, W1T, W2T);
  kasmina_fused<<<dim3(32, 64), 256, 0, stream>>>(
      Xb, Wbb, bbp, b1p, b2p, alpha, active, W1T, W2T, out);
}

// Round 5
// 314.901 us; speedup vs baseline: 1.9234x; 1.0859x over previous
//
#include <hip/hip_runtime.h>
#include <stdint.h>

typedef unsigned short u16;
typedef __bf16 bf16x8 __attribute__((ext_vector_type(8)));
typedef unsigned short u16x8 __attribute__((ext_vector_type(8)));
typedef u16x8 u16x8_ma __attribute__((may_alias));
typedef unsigned short u16x4 __attribute__((ext_vector_type(4)));
typedef float f32x4 __attribute__((ext_vector_type(4)));

#define DIN   1024
#define DOUT  4096
#define BM    128
#define BN    128
#define BK    64

__device__ __forceinline__ u16 f2bf(float f) {
  unsigned u = __float_as_uint(f);
  u += 0x7fffu + ((u >> 16) & 1u);   // round-to-nearest-even (finite inputs)
  return (u16)(u >> 16);
}
__device__ __forceinline__ bf16x8 ldfrag(const u16* p) {
  union { u16x8 u; bf16x8 b; } cv;
  cv.u = *(const u16x8_ma*)p;
  return cv.b;
}
__device__ __forceinline__ f32x4 mfma16(bf16x8 a, bf16x8 b, f32x4 c) {
  return __builtin_amdgcn_mfma_f32_16x16x32_bf16(a, b, c, 0, 0, 0);
}
__device__ __forceinline__ void gload_lds16(const u16* g, u16* l) {
  __builtin_amdgcn_global_load_lds(
      (const __attribute__((address_space(1))) void*)g,
      (__attribute__((address_space(3))) void*)l, 16, 0, 0);
}
// Wave-local LDS fence: same-wave DS ops execute in issue order; this only
// (a) stops compiler reordering, (b) waits outstanding DS ops. Much cheaper
// than __syncthreads (no inter-wave coupling, no vmcnt drain).
__device__ __forceinline__ void wave_lds_fence() {
  __asm__ __volatile__("s_waitcnt lgkmcnt(0)" ::: "memory");
}

// fp32 -> bf16 bulk convert (vectorized, grid-stride over float4s)
__global__ void cvt_f32_bf16(const float* __restrict__ src, u16* __restrict__ dst, int n4) {
  int i = blockIdx.x * blockDim.x + threadIdx.x;
  const int stride = gridDim.x * blockDim.x;
  for (; i < n4; i += stride) {
    f32x4 v = ((const f32x4*)src)[i];
    u16x4 o;
    o.x = f2bf(v.x); o.y = f2bf(v.y); o.z = f2bf(v.z); o.w = f2bf(v.w);
    ((u16x4*)dst)[i] = o;
  }
}

// Convert + transpose blueprint weights via LDS (coalesced global R and W):
// W1 [S][C][H] -> W1T [S][H][C] ;  W2 [S][H][C] -> W2T [S][C][H]
__global__ void prep_transpose(const float* __restrict__ W1, const float* __restrict__ W2,
                               u16* __restrict__ W1T, u16* __restrict__ W2T) {
  __shared__ u16 tile[8192];
  const int s = blockIdx.x;
  const int t = threadIdx.x;

  const float* w1 = W1 + s * 8192;
  u16* w1t = W1T + s * 8192;
  for (int i = t; i < 8192; i += 256) tile[i] = f2bf(w1[i]);   // coalesced read
  __syncthreads();
  for (int i = t; i < 8192; i += 256) {                        // coalesced write
    int h = i >> 6, c = i & 63;
    w1t[i] = tile[c * 128 + h];
  }
  __syncthreads();

  const float* w2 = W2 + s * 8192;
  u16* w2t = W2T + s * 8192;
  for (int i = t; i < 8192; i += 256) tile[i] = f2bf(w2[i]);
  __syncthreads();
  for (int i = t; i < 8192; i += 256) {
    int c = i >> 7, h = i & 127;
    w2t[i] = tile[h * 64 + c];
  }
}

// Fused: base = x@Wb^T + bb (128x128 tile, m97 structure + XOR-swizzled LDS),
// then per-wave (one seed per wave column-half) blueprint MLP + alpha blend.
// NOTES:
//  * every acc[] index must be compile-time constant (R3: scratch demotion,
//    2.3 GB HBM write amplification).
//  * LDS tile rows are 128 B: without swizzle a quad's 16 lanes hit the same
//    4 banks on ds_read_b128 (16-way conflict, R4: 2.6e7 conflict cycles).
//    Lane l stages global chunk (l&7)^(row&7); readers XOR chunk with row&7.
__global__ __launch_bounds__(256, 2) void kasmina_fused(
    const u16* __restrict__ X,   const u16* __restrict__ Wb,   // bf16 (pre-converted)
    const float* __restrict__ bb,  const float* __restrict__ b1,
    const float* __restrict__ b2,  const float* __restrict__ alpha,
    const int* __restrict__ active,
    const u16* __restrict__ W1T, const u16* __restrict__ W2T,  // bf16
    float* __restrict__ out)
{
  // LDS: staging As[128][64] @0, Bs[128][64] @8192. Epilogue reuses it as 4
  // wave-private regions of 4608 el: Ys[32][72] + Hs[32][72] (stride 72).
  __shared__ u16 lds[18432];

  const int t = threadIdx.x;
  const int w = t >> 6, l = t & 63;
  const int wm = w >> 1, wn = w & 1;
  const int lane15 = l & 15, quad = l >> 4;
  const int bn0 = blockIdx.x * BN;
  const int bm0 = blockIdx.y * BM;

  f32x4 acc[4][4];
#pragma unroll
  for (int mt = 0; mt < 4; ++mt)
#pragma unroll
    for (int nt = 0; nt < 4; ++nt)
      acc[mt][nt] = (f32x4){0.f, 0.f, 0.f, 0.f};

  // staging lane map with XOR swizzle: lane l covers row (l>>3) of its 8-row
  // chunk and global 8-col chunk ((l&7)^(row&7)); LDS slot stays base+16*l.
  const int srow = l >> 3;                  // 0..7, == row&7
  const int scol = ((l & 7) ^ srow) << 3;
  const u16* xg = X  + (size_t)(bm0 + srow) * DIN + scol;
  const u16* wg = Wb + (size_t)(bn0 + srow) * DIN + scol;

  // fragment-read swizzle: chunk' = (ks*4+quad) ^ (row&7); row&7 == lane15&7
  const int xr = lane15 & 7;
  const int oswz = (quad ^ xr) << 3;        // u16 offset, ks=0; ks=1: ^32
  const u16* Ab = &lds[(wm * 64 + lane15) * 64];
  const u16* Bb = &lds[8192 + (wn * 64 + lane15) * 64];

  for (int kt = 0; kt < DIN / BK; ++kt) {
    const int k0 = kt * BK;
#pragma unroll
    for (int i = 0; i < 4; ++i) {
      const int q = i * 4 + w;                       // chunk: rows q*8..q*8+7
      gload_lds16(xg + (size_t)(q * 8) * DIN + k0, &lds[q * 512]);
      gload_lds16(wg + (size_t)(q * 8) * DIN + k0, &lds[8192 + q * 512]);
    }
    __syncthreads();
#pragma unroll
    for (int ks = 0; ks < 2; ++ks) {
      const int o = oswz ^ (ks << 5);
      bf16x8 af[4], bfx[4];
#pragma unroll
      for (int mt = 0; mt < 4; ++mt) af[mt] = ldfrag(Ab + mt * 1024 + o);
#pragma unroll
      for (int nt = 0; nt < 4; ++nt) bfx[nt] = ldfrag(Bb + nt * 1024 + o);
#pragma unroll
      for (int mt = 0; mt < 4; ++mt)
#pragma unroll
        for (int nt = 0; nt < 4; ++nt)
          acc[mt][nt] = mfma16(af[mt], bfx[nt], acc[mt][nt]);
    }
    __syncthreads();   // final iter: also releases As/Bs for epilogue reuse
  }

  // ---------------- epilogue: per-seed MLP + blend ----------------
  const int sidx = blockIdx.x * 2 + wn;              // wave's seed
  const float al = alpha[sidx];
  const float aval = (active[sidx] != 0) ? al : 0.0f;
  float bbv[4];
#pragma unroll
  for (int nt = 0; nt < 4; ++nt) bbv[nt] = bb[sidx * 64 + nt * 16 + lane15];

  u16* Yw = &lds[w * 4608];        // [32][72] — wave-private
  u16* Hw = Yw + 2304;             // [32][72] — wave-private
  const size_t orow0 = (size_t)(bm0 + wm * 64);

#pragma unroll                      // MUST fully unroll: acc[] indices constant
  for (int mh = 0; mh < 2; ++mh) {  // 32-row halves
    // y (=base chunk incl. bias) -> LDS bf16, A-operand [m][c] layout.
#pragma unroll
    for (int mt = 0; mt < 2; ++mt)
#pragma unroll
      for (int nt = 0; nt < 4; ++nt) {
        f32x4 v = acc[mh * 2 + mt][nt];
        const int col = nt * 16 + lane15;
#pragma unroll
        for (int r = 0; r < 4; ++r)
          Yw[(mt * 16 + quad * 4 + r) * 72 + col] = f2bf(v[r] + bbv[nt]);
      }
    wave_lds_fence();              // Yw write -> read (wave-local)

    f32x4 bp[2][4];
#pragma unroll
    for (int nt = 0; nt < 4; ++nt) {
      const float b2v = b2[sidx * 64 + nt * 16 + lane15];
      const f32x4 tv = (f32x4){b2v, b2v, b2v, b2v};
      bp[0][nt] = tv; bp[1][nt] = tv;
    }

#pragma unroll 1
    for (int hh = 0; hh < 2; ++hh) {  // H=128 in two halves of 64
      f32x4 hc[2][4];
#pragma unroll
      for (int nt = 0; nt < 4; ++nt) {
        const float b1v = b1[sidx * 128 + hh * 64 + nt * 16 + lane15];
        const f32x4 tv = (f32x4){b1v, b1v, b1v, b1v};
        hc[0][nt] = tv; hc[1][nt] = tv;
      }
      // GEMM1: h = y @ W1_s   (M=32, N=64(half), K=64)
      const u16* w1b = W1T + sidx * 8192 + (hh * 64 + lane15) * 64 + quad * 8;
#pragma unroll
      for (int ks = 0; ks < 2; ++ks) {
        bf16x8 af0 = ldfrag(Yw + lane15 * 72 + ks * 32 + quad * 8);
        bf16x8 af1 = ldfrag(Yw + (16 + lane15) * 72 + ks * 32 + quad * 8);
#pragma unroll
        for (int nt = 0; nt < 4; ++nt) {
          bf16x8 bfr = ldfrag(w1b + nt * 1024 + ks * 32);   // L2-hot
          hc[0][nt] = mfma16(af0, bfr, hc[0][nt]);
          hc[1][nt] = mfma16(af1, bfr, hc[1][nt]);
        }
      }
      // relu -> bf16 -> Hs
#pragma unroll
      for (int mt = 0; mt < 2; ++mt)
#pragma unroll
        for (int nt = 0; nt < 4; ++nt) {
          f32x4 v = hc[mt][nt];
          const int col = nt * 16 + lane15;
#pragma unroll
          for (int r = 0; r < 4; ++r) {
            float hv = v[r] > 0.f ? v[r] : 0.f;
            Hw[(mt * 16 + quad * 4 + r) * 72 + col] = f2bf(hv);
          }
        }
      wave_lds_fence();            // Hw write -> read (wave-local)
      // GEMM2: bp += h @ W2_s[half]   (M=32, N=64, K=64)
      const u16* w2b = W2T + sidx * 8192 + lane15 * 128 + hh * 64 + quad * 8;
#pragma unroll
      for (int ks = 0; ks < 2; ++ks) {
        bf16x8 af0 = ldfrag(Hw + lane15 * 72 + ks * 32 + quad * 8);
        bf16x8 af1 = ldfrag(Hw + (16 + lane15) * 72 + ks * 32 + quad * 8);
#pragma unroll
        for (int nt = 0; nt < 4; ++nt) {
          bf16x8 bfr = ldfrag(w2b + nt * 2048 + ks * 32);
          bp[0][nt] = mfma16(af0, bfr, bp[0][nt]);
          bp[1][nt] = mfma16(af1, bfr, bp[1][nt]);
        }
      }
      wave_lds_fence();            // Hw read -> next-iter write (WAR)
    }
    // blend (y in fp32 from acc, unquantized) + fp32 store
#pragma unroll
    for (int mt = 0; mt < 2; ++mt)
#pragma unroll
      for (int nt = 0; nt < 4; ++nt) {
        f32x4 yv = acc[mh * 2 + mt][nt];
        f32x4 pv = bp[mt][nt];
        const int col = sidx * 64 + nt * 16 + lane15;
#pragma unroll
        for (int r = 0; r < 4; ++r) {
          const float y = yv[r] + bbv[nt];
          const float o = (1.0f - aval) * y + aval * pv[r];
          const size_t row = orow0 + mh * 32 + mt * 16 + quad * 4 + r;
          out[row * DOUT + col] = o;
        }
      }
    wave_lds_fence();              // Yw/Hw reuse for next half (WAR)
  }
}

extern "C" void kernel_launch(void* const* d_in, const int* in_sizes, int n_in,
                              void* d_out, int out_size, void* d_ws, size_t ws_size,
                              hipStream_t stream) {
  const float* X     = (const float*)d_in[0];   // [8192][1024] fp32
  const float* Wb    = (const float*)d_in[1];   // [4096][1024] fp32
  const float* bbp   = (const float*)d_in[2];   // [4096]
  const float* W1    = (const float*)d_in[3];   // [64][64][128]
  const float* b1p   = (const float*)d_in[4];   // [64][128]
  const float* W2    = (const float*)d_in[5];   // [64][128][64]
  const float* b2p   = (const float*)d_in[6];   // [64][64]
  const float* alpha = (const float*)d_in[7];   // [64]
  const int*  active = (const int*)d_in[8];     // [64]
  float* out = (float*)d_out;

  // workspace layout (u16 units): W1T 512K | W2T 512K | Xb 8.39M | Wbb 4.19M
  u16* W1T = (u16*)d_ws;
  u16* W2T = W1T + 524288;
  u16* Xb  = W1T + 1048576;
  u16* Wbb = W1T + 9437184;       // total ~27.3 MB

  cvt_f32_bf16<<<2048, 256, 0, stream>>>(X,  Xb,  (8192 * 1024) / 4);
  cvt_f32_bf16<<<1024, 256, 0, stream>>>(Wb, Wbb, (4096 * 1024) / 4);
  prep_transpose<<<64, 256, 0, stream>>>(W1, W2, W1T, W2T);
  kasmina_fused<<<dim3(32, 64), 256, 0, stream>>>(
      Xb, Wbb, bbp, b1p, b2p, alpha, active, W1T, W2T, out);
}